// Round 1
// baseline (499.825 us; speedup 1.0000x reference)
//
#include <hip/hip_runtime.h>
#include <hip/hip_fp16.h>

#define B_ 4096
#define T_ 64
#define F_ 128
#define NROWS (B_*T_)   // 262144

typedef _Float16 f16x8 __attribute__((ext_vector_type(8)));
typedef float    f32x4 __attribute__((ext_vector_type(4)));

__device__ __forceinline__ float gelu_f(float x){
    return 0.5f * x * (1.0f + erff(x * 0.70710678118654752f));
}

// ---- stage W (K x 128, row-major f32) transposed into LDS as f16:
// WT[c][k] at byte c*(2K) + ((2k) ^ ((c&7)<<4))
__device__ __forceinline__ void stage_wt(const float* __restrict__ w,
                                         unsigned short* buf, int K, int tid){
    const int total = K * 128;
    const int K2 = K * 2;
    for (int idx = tid; idx < total; idx += 512){
        int k = idx >> 7, cc = idx & 127;
        _Float16 v = (_Float16)w[idx];
        int byte = cc * K2 + ((k << 1) ^ ((cc & 7) << 4));
        *(_Float16*)((char*)buf + byte) = v;
    }
}

// ---- stage W2 (128 x 2) transposed+padded to WT[16][128] (rows 2..15 zero)
__device__ __forceinline__ void stage_w2(const float* __restrict__ w,
                                         unsigned short* buf, int tid){
    for (int idx = tid; idx < 2048; idx += 512){
        int r = idx >> 7, k = idx & 127;
        float v = (r < 2) ? w[k * 2 + r] : 0.f;
        int byte = r * 256 + ((k << 1) ^ ((r & 7) << 4));
        *(_Float16*)((char*)buf + byte) = (_Float16)v;
    }
}

template<int NT, int NKS>
__device__ __forceinline__ void mfma_block(f32x4* acc, const f16x8* a,
                                           const char* wb, int stride, int c, int g){
#pragma unroll
    for (int n = 0; n < NT; n++){
        const int r = n * 16 + c;
        const char* rp = wb + r * stride;
        const int swz = (r & 7) << 4;
#pragma unroll
        for (int ks = 0; ks < NKS; ks++){
            f16x8 b = *(const f16x8*)(rp + ((ks * 64 + g * 16) ^ swz));
            acc[n] = __builtin_amdgcn_mfma_f32_16x16x32_f16(a[ks], b, acc[n], 0, 0, 0);
        }
    }
}

// ======================= stats kernel: counts -> ent/sv/tot per t ==========
__global__ void k_stats(const int* __restrict__ mask, const int* __restrict__ labels,
                        float* __restrict__ ws){
    int t = blockIdx.x, tid = threadIdx.x;
    float c0 = 0.f, c1 = 0.f;
    for (int b = tid; b < B_; b += 256){
        if (mask[b * T_ + t]){
            if (labels[b] == 1) c1 += 1.f; else c0 += 1.f;
        }
    }
    for (int m = 1; m < 64; m <<= 1){ c0 += __shfl_xor(c0, m); c1 += __shfl_xor(c1, m); }
    __shared__ float sh[8];
    int w = tid >> 6, l = tid & 63;
    if (l == 0){ sh[w] = c0; sh[4 + w] = c1; }
    __syncthreads();
    if (tid == 0){
        float a0 = sh[0] + sh[1] + sh[2] + sh[3];
        float a1 = sh[4] + sh[5] + sh[6] + sh[7];
        float tot = a0 + a1;
        float d = fmaxf(tot, 1.f);
        float p0 = a0 / d, p1 = a1 / d;
        float ent = -(p0 * logf(p0 + 1e-8f) + p1 * logf(p1 + 1e-8f));
        ws[t] = ent;                       // ent[64]
        ws[64 + t] = (tot >= 2.f) ? 1.f : 0.f;  // step_valid[64]
        ws[128 + t] = tot;                 // tot[64]
    }
}

// ======================= main fused kernel ================================
__global__ __launch_bounds__(512, 2) void k_main(
    const float* __restrict__ xc, const float* __restrict__ xs,
    const int* __restrict__ labels, const int* __restrict__ mask,
    const float* __restrict__ ce_w1, const float* __restrict__ ce_b1,
    const float* __restrict__ ce_w2, const float* __restrict__ ce_b2,
    const float* __restrict__ se_w1, const float* __restrict__ se_b1,
    const float* __restrict__ se_w2, const float* __restrict__ se_b2,
    const float* __restrict__ cd_g,  const float* __restrict__ cd_bt,
    const float* __restrict__ cd_w1, const float* __restrict__ cd_b1,
    const float* __restrict__ cd_w2, const float* __restrict__ cd_b2,
    const float* __restrict__ jd_g,  const float* __restrict__ jd_bt,
    const float* __restrict__ jd_w1, const float* __restrict__ jd_b1,
    const float* __restrict__ jd_w2, const float* __restrict__ jd_b2,
    float* __restrict__ ws, float* __restrict__ out)
{
    // LDS: wbuf 64KB (layer weights), w2 pads 8KB, abuf 64KB (8 waves x [16][256] f16), biases
    __shared__ __align__(16) unsigned short wbuf[128 * 256];
    __shared__ __align__(16) unsigned short w2c[16 * 128];
    __shared__ __align__(16) unsigned short w2j[16 * 128];
    __shared__ __align__(16) unsigned short abuf[8 * 16 * 256];
    __shared__ float sb[1792];
    // sb: 0 ce_b1 | 128 ce_b2 | 256 se_b1 | 384 se_b2 | 512 cd_g | 640 cd_b
    //     768 cd_b1 | 896 cd_b2(2) | 1024 jd_g(256) | 1280 jd_b(256) | 1536 jd_b1 | 1664 jd_b2(2)

    const int tid = threadIdx.x;
    const int wave = tid >> 6, lane = tid & 63;
    const int c = lane & 15, g = lane >> 4;
    const int wrow0 = blockIdx.x * 128 + wave * 16;
    char* const ab = (char*)abuf + wave * 8192;
    const int rswz = (c & 7) << 4;

    // ---- phase 0 staging: encoder L1 weights (both), W2 pads, biases
    stage_wt(ce_w1, wbuf, 128, tid);
    stage_wt(se_w1, wbuf + 16384, 128, tid);
    stage_w2(cd_w2, w2c, tid);
    stage_w2(jd_w2, w2j, tid);
    if (tid < 128){
        sb[tid] = ce_b1[tid]; sb[128 + tid] = ce_b2[tid];
        sb[256 + tid] = se_b1[tid]; sb[384 + tid] = se_b2[tid];
        sb[512 + tid] = cd_g[tid]; sb[640 + tid] = cd_bt[tid];
        sb[768 + tid] = cd_b1[tid]; sb[1536 + tid] = jd_b1[tid];
    } else if (tid < 384){
        int i = tid - 128; sb[1024 + i] = jd_g[i]; sb[1280 + i] = jd_bt[i];
    } else if (tid < 386){
        int i = tid - 384; sb[896 + i] = cd_b2[i]; sb[1664 + i] = jd_b2[i];
    }
    __syncthreads();

    const int lab = labels[(wrow0 + g * 4) >> 6];

    f16x8 a[8];
    f32x4 accW[8], accC[8], accS[8];

    // ================= encoder layer 1 (causal) =================
#pragma unroll
    for (int ks = 0; ks < 4; ks++){
        const float* p = xc + (wrow0 + c) * 128 + ks * 32 + g * 8;
        float4 v0 = *(const float4*)p, v1 = *(const float4*)(p + 4);
        f16x8 t;
        t[0]=(_Float16)v0.x; t[1]=(_Float16)v0.y; t[2]=(_Float16)v0.z; t[3]=(_Float16)v0.w;
        t[4]=(_Float16)v1.x; t[5]=(_Float16)v1.y; t[6]=(_Float16)v1.z; t[7]=(_Float16)v1.w;
        a[ks] = t;
    }
#pragma unroll
    for (int n = 0; n < 8; n++) accW[n] = (f32x4){0.f,0.f,0.f,0.f};
    mfma_block<8,4>(accW, a, (const char*)wbuf, 256, c, g);
#pragma unroll
    for (int n = 0; n < 8; n++){
        float bi = sb[n * 16 + c];
#pragma unroll
        for (int rr = 0; rr < 4; rr++){
            float v = gelu_f(accW[n][rr] + bi);
            int row = g * 4 + rr;
            *(_Float16*)(ab + row * 512 + (((n * 16 + c) << 1) ^ ((row & 7) << 4))) = (_Float16)v;
        }
    }

    // ================= encoder layer 1 (spurious) -> abuf cols 128..255 =====
#pragma unroll
    for (int ks = 0; ks < 4; ks++){
        const float* p = xs + (wrow0 + c) * 128 + ks * 32 + g * 8;
        float4 v0 = *(const float4*)p, v1 = *(const float4*)(p + 4);
        f16x8 t;
        t[0]=(_Float16)v0.x; t[1]=(_Float16)v0.y; t[2]=(_Float16)v0.z; t[3]=(_Float16)v0.w;
        t[4]=(_Float16)v1.x; t[5]=(_Float16)v1.y; t[6]=(_Float16)v1.z; t[7]=(_Float16)v1.w;
        a[ks] = t;
    }
#pragma unroll
    for (int n = 0; n < 8; n++) accW[n] = (f32x4){0.f,0.f,0.f,0.f};
    mfma_block<8,4>(accW, a, (const char*)wbuf + 32768, 256, c, g);
#pragma unroll
    for (int n = 0; n < 8; n++){
        float bi = sb[256 + n * 16 + c];
#pragma unroll
        for (int rr = 0; rr < 4; rr++){
            float v = gelu_f(accW[n][rr] + bi);
            int row = g * 4 + rr;
            *(_Float16*)(ab + row * 512 + (((n * 16 + c + 128) << 1) ^ ((row & 7) << 4))) = (_Float16)v;
        }
    }

    __syncthreads();
    stage_wt(ce_w2, wbuf, 128, tid);
    stage_wt(se_w2, wbuf + 16384, 128, tid);
    __syncthreads();

    // ================= encoder layer 2 -> c_rep / s_rep in registers ========
#pragma unroll
    for (int ks = 0; ks < 4; ks++)
        a[ks] = *(const f16x8*)(ab + c * 512 + ((ks * 64 + g * 16) ^ rswz));
#pragma unroll
    for (int n = 0; n < 8; n++) accC[n] = (f32x4){0.f,0.f,0.f,0.f};
    mfma_block<8,4>(accC, a, (const char*)wbuf, 256, c, g);
#pragma unroll
    for (int n = 0; n < 8; n++){
        float bi = sb[128 + n * 16 + c];
#pragma unroll
        for (int rr = 0; rr < 4; rr++) accC[n][rr] += bi;
    }

#pragma unroll
    for (int ks = 0; ks < 4; ks++)
        a[ks] = *(const f16x8*)(ab + c * 512 + ((256 + ks * 64 + g * 16) ^ rswz));
#pragma unroll
    for (int n = 0; n < 8; n++) accS[n] = (f32x4){0.f,0.f,0.f,0.f};
    mfma_block<8,4>(accS, a, (const char*)wbuf + 32768, 256, c, g);
#pragma unroll
    for (int n = 0; n < 8; n++){
        float bi = sb[384 + n * 16 + c];
#pragma unroll
        for (int rr = 0; rr < 4; rr++) accS[n][rr] += bi;
    }

    // ================= LN(c_rep) -> abuf cols 0..127 ========================
    {
        float s0[4] = {0,0,0,0}, s1[4] = {0,0,0,0};
#pragma unroll
        for (int n = 0; n < 8; n++)
#pragma unroll
            for (int rr = 0; rr < 4; rr++){ float v = accC[n][rr]; s0[rr] += v; s1[rr] += v * v; }
#pragma unroll
        for (int rr = 0; rr < 4; rr++){
#pragma unroll
            for (int m = 1; m < 16; m <<= 1){ s0[rr] += __shfl_xor(s0[rr], m); s1[rr] += __shfl_xor(s1[rr], m); }
        }
        float mean[4], rstd[4];
#pragma unroll
        for (int rr = 0; rr < 4; rr++){
            mean[rr] = s0[rr] * (1.f / 128.f);
            float var = s1[rr] * (1.f / 128.f) - mean[rr] * mean[rr];
            rstd[rr] = rsqrtf(var + 1e-5f);
        }
#pragma unroll
        for (int n = 0; n < 8; n++){
            int col = n * 16 + c;
#pragma unroll
            for (int rr = 0; rr < 4; rr++){
                float y = (accC[n][rr] - mean[rr]) * rstd[rr] * sb[512 + col] + sb[640 + col];
                int row = g * 4 + rr;
                *(_Float16*)(ab + row * 512 + ((col << 1) ^ ((row & 7) << 4))) = (_Float16)y;
            }
        }
    }

    __syncthreads();
    stage_wt(cd_w1, wbuf, 128, tid);
    __syncthreads();

    // ================= causal decoder hidden -> abuf cols 128..255 ==========
#pragma unroll
    for (int ks = 0; ks < 4; ks++)
        a[ks] = *(const f16x8*)(ab + c * 512 + ((ks * 64 + g * 16) ^ rswz));
#pragma unroll
    for (int n = 0; n < 8; n++) accW[n] = (f32x4){0.f,0.f,0.f,0.f};
    mfma_block<8,4>(accW, a, (const char*)wbuf, 256, c, g);
#pragma unroll
    for (int n = 0; n < 8; n++){
        float bi = sb[768 + n * 16 + c];
#pragma unroll
        for (int rr = 0; rr < 4; rr++){
            float v = gelu_f(accW[n][rr] + bi);
            int row = g * 4 + rr;
            *(_Float16*)(ab + row * 512 + (((n * 16 + c + 128) << 1) ^ ((row & 7) << 4))) = (_Float16)v;
        }
    }

    // ================= causal logits + CE ===================================
    float ceC[4], ceJ[4];
    {
#pragma unroll
        for (int ks = 0; ks < 4; ks++)
            a[ks] = *(const f16x8*)(ab + c * 512 + ((256 + ks * 64 + g * 16) ^ rswz));
        f32x4 accL = (f32x4){0.f,0.f,0.f,0.f};
        const char* rp = (const char*)w2c + c * 256;
#pragma unroll
        for (int ks = 0; ks < 4; ks++){
            f16x8 b = *(const f16x8*)(rp + ((ks * 64 + g * 16) ^ rswz));
            accL = __builtin_amdgcn_mfma_f32_16x16x32_f16(a[ks], b, accL, 0, 0, 0);
        }
#pragma unroll
        for (int rr = 0; rr < 4; rr++){
            float lg = accL[rr] + ((c < 2) ? sb[896 + c] : 0.f);
            float ot = __shfl_xor(lg, 1);
            float mx = fmaxf(lg, ot);
            float lse = mx + logf(expf(lg - mx) + expf(ot - mx));
            ceC[rr] = lse - ((lab == c) ? lg : ot);
        }
    }

    // ================= joint LN (256) -> abuf cols 0..255 ===================
    {
        float s0[4] = {0,0,0,0}, s1[4] = {0,0,0,0};
#pragma unroll
        for (int n = 0; n < 8; n++)
#pragma unroll
            for (int rr = 0; rr < 4; rr++){
                float v = accC[n][rr]; s0[rr] += v; s1[rr] += v * v;
                float u = accS[n][rr]; s0[rr] += u; s1[rr] += u * u;
            }
#pragma unroll
        for (int rr = 0; rr < 4; rr++){
#pragma unroll
            for (int m = 1; m < 16; m <<= 1){ s0[rr] += __shfl_xor(s0[rr], m); s1[rr] += __shfl_xor(s1[rr], m); }
        }
        float mean[4], rstd[4];
#pragma unroll
        for (int rr = 0; rr < 4; rr++){
            mean[rr] = s0[rr] * (1.f / 256.f);
            float var = s1[rr] * (1.f / 256.f) - mean[rr] * mean[rr];
            rstd[rr] = rsqrtf(var + 1e-5f);
        }
#pragma unroll
        for (int n = 0; n < 8; n++){
            int col = n * 16 + c;
#pragma unroll
            for (int rr = 0; rr < 4; rr++){
                int row = g * 4 + rr;
                float yc = (accC[n][rr] - mean[rr]) * rstd[rr] * sb[1024 + col] + sb[1280 + col];
                float ys = (accS[n][rr] - mean[rr]) * rstd[rr] * sb[1024 + 128 + col] + sb[1280 + 128 + col];
                *(_Float16*)(ab + row * 512 + ((col << 1) ^ ((row & 7) << 4))) = (_Float16)yc;
                *(_Float16*)(ab + row * 512 + (((col + 128) << 1) ^ ((row & 7) << 4))) = (_Float16)ys;
            }
        }
    }

    __syncthreads();
    stage_wt(jd_w1, wbuf, 256, tid);   // [256][128] -> WT[128][256], stride 512B
    __syncthreads();

    // ================= joint decoder hidden (K=256) -> abuf cols 0..127 =====
#pragma unroll
    for (int ks = 0; ks < 8; ks++)
        a[ks] = *(const f16x8*)(ab + c * 512 + ((ks * 64 + g * 16) ^ rswz));
#pragma unroll
    for (int n = 0; n < 8; n++) accW[n] = (f32x4){0.f,0.f,0.f,0.f};
    mfma_block<8,8>(accW, a, (const char*)wbuf, 512, c, g);
#pragma unroll
    for (int n = 0; n < 8; n++){
        float bi = sb[1536 + n * 16 + c];
#pragma unroll
        for (int rr = 0; rr < 4; rr++){
            float v = gelu_f(accW[n][rr] + bi);
            int row = g * 4 + rr;
            *(_Float16*)(ab + row * 512 + (((n * 16 + c) << 1) ^ ((row & 7) << 4))) = (_Float16)v;
        }
    }

    // ================= joint logits + CE ====================================
    {
#pragma unroll
        for (int ks = 0; ks < 4; ks++)
            a[ks] = *(const f16x8*)(ab + c * 512 + ((ks * 64 + g * 16) ^ rswz));
        f32x4 accL = (f32x4){0.f,0.f,0.f,0.f};
        const char* rp = (const char*)w2j + c * 256;
#pragma unroll
        for (int ks = 0; ks < 4; ks++){
            f16x8 b = *(const f16x8*)(rp + ((ks * 64 + g * 16) ^ rswz));
            accL = __builtin_amdgcn_mfma_f32_16x16x32_f16(a[ks], b, accL, 0, 0, 0);
        }
#pragma unroll
        for (int rr = 0; rr < 4; rr++){
            float lg = accL[rr] + ((c < 2) ? sb[1664 + c] : 0.f);
            float ot = __shfl_xor(lg, 1);
            float mx = fmaxf(lg, ot);
            float lse = mx + logf(expf(lg - mx) + expf(ot - mx));
            ceJ[rr] = lse - ((lab == c) ? lg : ot);
        }
    }

    // ================= reward + masked-CE outputs (lane c==0 writes 4 rows) ==
    if (c == 0){
        int rowbase = wrow0 + g * 4;
        const int4 m4 = *(const int4*)(mask + rowbase);
        const float4 e4 = *(const float4*)(ws + (rowbase & 63));
        const float4 s4 = *(const float4*)(ws + 64 + (rowbase & 63));
        const int   mm[4] = {m4.x, m4.y, m4.z, m4.w};
        const float ee[4] = {e4.x, e4.y, e4.z, e4.w};
        const float sv[4] = {s4.x, s4.y, s4.z, s4.w};
        float rw[4], mc[4], mj[4];
#pragma unroll
        for (int rr = 0; rr < 4; rr++){
            float mf = mm[rr] ? 1.f : 0.f;
            float cec = ceC[rr], cej = ceJ[rr];
            rw[rr] = mf * sv[rr] * (ee[rr] - cec - 0.5f * fmaxf(cec - cej, 0.f));
            mc[rr] = mf * cec;
            mj[rr] = mf * cej;
        }
        *(float4*)(out + rowbase)               = (float4){rw[0], rw[1], rw[2], rw[3]};
        *(float4*)(ws + 256 + rowbase)          = (float4){mc[0], mc[1], mc[2], mc[3]};
        *(float4*)(ws + 256 + NROWS + rowbase)  = (float4){mj[0], mj[1], mj[2], mj[3]};
    }
}

// ======================= aux reductions ===================================
__global__ void k_aux1(float* __restrict__ ws){
    int t = blockIdx.x, tid = threadIdx.x;
    const float* mc = ws + 256;
    const float* mj = ws + 256 + NROWS;
    float sc = 0.f, sj = 0.f;
    for (int b = tid; b < B_; b += 256){ sc += mc[b * T_ + t]; sj += mj[b * T_ + t]; }
    for (int m = 1; m < 64; m <<= 1){ sc += __shfl_xor(sc, m); sj += __shfl_xor(sj, m); }
    __shared__ float sh[8];
    int w = tid >> 6, l = tid & 63;
    if (l == 0){ sh[w] = sc; sh[4 + w] = sj; }
    __syncthreads();
    if (tid == 0){
        float a0 = sh[0] + sh[1] + sh[2] + sh[3];
        float a1 = sh[4] + sh[5] + sh[6] + sh[7];
        ws[192 + t] = ws[64 + t] * 0.5f * (a0 + a1) / fmaxf(ws[128 + t], 1.f);
    }
}

__global__ void k_aux2(const float* __restrict__ ws, float* __restrict__ out){
    int l = threadIdx.x;   // 64 threads = 1 wave
    float cv = ws[192 + l], sv = ws[64 + l];
    for (int m = 1; m < 64; m <<= 1){ cv += __shfl_xor(cv, m); sv += __shfl_xor(sv, m); }
    if (l == 0) out[NROWS] = (sv > 0.f) ? cv / fmaxf(sv, 1.f) : 0.f;
}

extern "C" void kernel_launch(void* const* d_in, const int* in_sizes, int n_in,
                              void* d_out, int out_size, void* d_ws, size_t ws_size,
                              hipStream_t stream) {
    const float* xc     = (const float*)d_in[0];
    const float* xs     = (const float*)d_in[1];
    const int*   labels = (const int*)d_in[2];
    const int*   mask   = (const int*)d_in[3];
    const float* ce_w1  = (const float*)d_in[4];
    const float* ce_b1  = (const float*)d_in[5];
    const float* ce_w2  = (const float*)d_in[6];
    const float* ce_b2  = (const float*)d_in[7];
    const float* se_w1  = (const float*)d_in[8];
    const float* se_b1  = (const float*)d_in[9];
    const float* se_w2  = (const float*)d_in[10];
    const float* se_b2  = (const float*)d_in[11];
    const float* cd_g   = (const float*)d_in[12];
    const float* cd_b   = (const float*)d_in[13];
    const float* cd_w1  = (const float*)d_in[14];
    const float* cd_b1  = (const float*)d_in[15];
    const float* cd_w2  = (const float*)d_in[16];
    const float* cd_b2  = (const float*)d_in[17];
    const float* jd_g   = (const float*)d_in[18];
    const float* jd_b   = (const float*)d_in[19];
    const float* jd_w1  = (const float*)d_in[20];
    const float* jd_b1  = (const float*)d_in[21];
    const float* jd_w2  = (const float*)d_in[22];
    const float* jd_b2  = (const float*)d_in[23];
    float* ws  = (float*)d_ws;
    float* out = (float*)d_out;

    k_stats<<<64, 256, 0, stream>>>(mask, labels, ws);
    k_main<<<2048, 512, 0, stream>>>(xc, xs, labels, mask,
                                     ce_w1, ce_b1, ce_w2, ce_b2,
                                     se_w1, se_b1, se_w2, se_b2,
                                     cd_g, cd_b, cd_w1, cd_b1, cd_w2, cd_b2,
                                     jd_g, jd_b, jd_w1, jd_b1, jd_w2, jd_b2,
                                     ws, out);
    k_aux1<<<64, 256, 0, stream>>>(ws);
    k_aux2<<<1, 64, 0, stream>>>(ws, out);
}